// Round 9
// baseline (253.397 us; speedup 1.0000x reference)
//
#include <hip/hip_runtime.h>
#include <stdint.h>
#include <stddef.h>

#define A_N 384
#define F_N 128
#define C_N 32
#define H_N 512
#define LN_EPS 1e-5f

typedef unsigned short u16;
typedef _Float16 f16;
typedef f16 f16x8 __attribute__((ext_vector_type(8)));
typedef float f32x4 __attribute__((ext_vector_type(4)));

// ---- scratch in static device memory (d_ws unused) ----
__device__ f16   gLh[A_N * C_N];            // left proj, f16 [a][c]
__device__ f16   gRh[A_N * C_N];            // right proj, f16 [b][d]
__device__ f16   gWoT[F_N * C_N * C_N];     // [fc_lin=f*32+c][d] = w_out[(c*32+d)*128+f], f16
__device__ f16   gMh[A_N * F_N * C_N];      // [b][f][c] f16 (c-contiguous = MFMA B-frag ready)
__device__ int4  gW1P[16 * 512];            // per-chunk pre-swizzled W1 LDS images (8KB each)
__device__ int4  gW2P[16 * 768];            // per-chunk W2 LDS images (12KB stride, 10240B real)

__device__ __forceinline__ float b2f(u16 u) {
    union { float f; uint32_t i; } v; v.i = ((uint32_t)u) << 16; return v.f;
}
__device__ __forceinline__ float ld(const void* p, int idx, bool isbf) {
    if (isbf) return b2f(((const u16*)p)[idx]);
    return ((const float*)p)[idx];
}
__device__ __forceinline__ bool probe_bf16(const void* node_mask) {
    return ((const u16*)node_mask)[0] == 0x3F80u;   // 1.0 bf16; fp32 LE low half is 0x0000
}
__device__ __forceinline__ f16x8 ldfrag(const void* p) {
    union { int4 i; f16x8 h; } u; u.i = *(const int4*)p; return u.h;
}
// async global->LDS DMA, 16B per lane; lds dst must be wave-uniform base (HW adds lane*16)
__device__ __forceinline__ void gload16(const void* gsrc, void* ldst) {
    __builtin_amdgcn_global_load_lds(
        (const __attribute__((address_space(1))) void*)gsrc,
        (__attribute__((address_space(3))) void*)ldst, 16, 0, 0);
}

// ---------------- K1: k_pre — all independent prep, 128 thr/block (unchanged) ----------------
__global__ __launch_bounds__(128) void k_pre(
    const void* __restrict__ node_vec, const void* __restrict__ node_mask,
    const void* __restrict__ op_scale, const void* __restrict__ op_bias,
    const void* __restrict__ w_left, const void* __restrict__ b_left,
    const void* __restrict__ w_right, const void* __restrict__ b_right,
    const void* __restrict__ w_out, const void* __restrict__ w_t1,
    const void* __restrict__ w_t2) {
    bool isbf = probe_bf16(node_mask);
    const int t = threadIdx.x;
    if (blockIdx.x < 384) {
        __shared__ float sAct[F_N];
        __shared__ float sRed[4];
        int a = blockIdx.x;
        int f = t;                      // 128 threads = 2 waves
        float x = ld(node_vec, a * F_N + f, isbf);
        float s1 = x, s2 = x * x;
        for (int o = 1; o < 64; o <<= 1) { s1 += __shfl_xor(s1, o); s2 += __shfl_xor(s2, o); }
        int wv = t >> 6;
        if ((t & 63) == 0) { sRed[wv * 2] = s1; sRed[wv * 2 + 1] = s2; }
        __syncthreads();
        float sum = sRed[0] + sRed[2], sq = sRed[1] + sRed[3];
        float mu = sum * (1.0f / F_N);
        float var = sq * (1.0f / F_N) - mu * mu;
        float rs = rsqrtf(var + LN_EPS);
        sAct[f] = (x - mu) * rs * ld(op_scale, f, isbf) + ld(op_bias, f, isbf);
        __syncthreads();
        if (t < 64) {
            int c = t & 31;
            bool isL = t < 32;
            const void* W = isL ? w_left : w_right;
            const void* B = isL ? b_left : b_right;
            float acc = ld(B, c, isbf);
            for (int ff = 0; ff < F_N; ff++) acc += sAct[ff] * ld(W, ff * C_N + c, isbf);
            acc *= ld(node_mask, a, isbf);
            if (isL) gLh[a * C_N + c] = (f16)acc;
            else     gRh[a * C_N + c] = (f16)acc;
        }
    } else if (blockIdx.x < 448) {
        int s = (blockIdx.x - 384) * 128 + t;       // 0..8191
        int ch = s >> 9, r = s & 511, n = r >> 4, sgq = r & 15;
        int h = ch * 32 + n;
        union { int4 i; f16 hh[8]; } u;
        #pragma unroll
        for (int e = 0; e < 8; e++) u.hh[e] = (f16)ld(w_t1, (sgq * 8 + e) * H_N + h, isbf);
        gW1P[ch * 512 + n * 16 + (sgq ^ (n & 7))] = u.i;
    } else if (blockIdx.x < 512) {
        int s = (blockIdx.x - 448) * 128 + t;       // 0..8191
        int ch = s >> 9, r = s & 511, f = r >> 2, hb = r & 3;
        union { int4 i; f16 hh[8]; } u;
        #pragma unroll
        for (int e = 0; e < 8; e++) u.hh[e] = (f16)ld(w_t2, (ch * 32 + hb * 8 + e) * F_N + f, isbf);
        gW2P[(size_t)ch * 768 + f * 5 + hb] = u.i;
    } else {
        int row = (blockIdx.x - 512) * 128 + t;     // 0..4095
        int c = row & 31, f = row >> 5;
        union { int4 i4[4]; f16 h[32]; } u;
        #pragma unroll
        for (int d = 0; d < 32; d++) u.h[d] = (f16)ld(w_out, (c * 32 + d) * F_N + f, isbf);
        int4* dst = (int4*)(gWoT + (size_t)row * 32);
        dst[0] = u.i4[0]; dst[1] = u.i4[1]; dst[2] = u.i4[2]; dst[3] = u.i4[3];
    }
}

// ---------------- K2: k_mgemm — M[b][fc] = sum_d gRh[b,d] * gWoT[fc,d] via MFMA (unchanged) ----
__global__ __launch_bounds__(256) void k_mgemm() {
    const int t = threadIdx.x;
    const int lane = t & 63, wid = t >> 6;
    const int g = lane >> 4, fc = lane & 15;
    const int bw = wid >> 1, cw = wid & 1;
    const int bg = blockIdx.x >> 4, fg = blockIdx.x & 15;   // 12 x 16 blocks
    const int b0w = bg * 32 + bw * 16;
    const int fc0 = fg * 256 + cw * 128;
    const f32x4 zero4 = (f32x4){0.f, 0.f, 0.f, 0.f};

    f16x8 afr = ldfrag(gRh + (b0w + fc) * C_N + g * 8);
    f32x4 acc[8];
    #pragma unroll
    for (int nc = 0; nc < 8; nc++) {
        f16x8 bfr = ldfrag(gWoT + (size_t)(fc0 + nc * 16 + fc) * 32 + g * 8);
        acc[nc] = __builtin_amdgcn_mfma_f32_16x16x32_f16(afr, bfr, zero4, 0, 0, 0);
    }
    #pragma unroll
    for (int nc = 0; nc < 8; nc++) {
        int col = fc0 + nc * 16 + fc;
        #pragma unroll
        for (int rg = 0; rg < 4; rg++) {
            int b = b0w + g * 4 + rg;
            gMh[(size_t)b * 4096 + col] = (f16)acc[nc][rg];
        }
    }
}

// ---------------- K3: fused — wave-owns-one-b restructure ----------------
// 256 threads = 4 waves. Tile = 64 rows = 4 b x 16 a; wave wid owns b = b0+wid (16 rows).
// All intra-chunk deps are wave-local (H produced+consumed by same wave; LN wave-local)
// -> ONE barrier per chunk (buffer switch + DMA drain), DMA hidden under full chunk.
// LDS: sX 16KB @0 (becomes W1 dbuf 2x8KB) | W2 dbuf 2x12288 @16384 | H 64x80B @40960 | consts.
#define SM_W1   0
#define SM_W2   16384
#define SM_H    40960    // 64 rows x 80B = 5120
#define SM_B1   46080
#define SM_SCL  48128
#define SM_BIA  48640
#define SM_B2   49152
#define SM_BOUT 49664
#define SM_TOT  50176

__global__ __launch_bounds__(256, 3) void k_fused(
    const void* __restrict__ edge_vec, const void* __restrict__ b_out,
    const void* __restrict__ tr_scale, const void* __restrict__ tr_bias,
    const void* __restrict__ b_t1, const void* __restrict__ b_t2,
    const void* __restrict__ node_mask, float* __restrict__ out)
{
    bool isbf = probe_bf16(node_mask);
    __shared__ __align__(16) unsigned char smem[SM_TOT];
    float* sB1    = (float*)(smem + SM_B1);
    float* sScale = (float*)(smem + SM_SCL);
    float* sBias  = (float*)(smem + SM_BIA);
    float* sB2    = (float*)(smem + SM_B2);
    float* sBout  = (float*)(smem + SM_BOUT);

    const int t = threadIdx.x;               // 256 threads = 4 waves
    const int lane = t & 63, wid = t >> 6;
    const int g = lane >> 4, fc = lane & 15;

    // Bijective XCD remap: 2304 blocks = 8 xcd x (12 bx x 24 by)
    const int L = blockIdx.x;
    const int xcd = L & 7, pos = L >> 3;
    const int bx = xcd * 12 + (pos % 12);
    const int by = pos / 12;
    const int a0 = by * 16, b0 = bx * 4;
    const int b = b0 + wid;                  // this wave's b

    // ---- phase 0: consts ----
    sB1[t]       = ld(b_t1, t, isbf);
    sB1[t + 256] = ld(b_t1, t + 256, isbf);
    if (t < 128) {
        sScale[t] = ld(tr_scale, t, isbf);
        sBias[t]  = ld(tr_bias, t, isbf);
        sB2[t]    = ld(b_t2, t, isbf);
        sBout[t]  = ld(b_out, t, isbf);
    }
    __syncthreads();

    // ---- phase 1: E via MFMA, acc2[8] covers this wave's 16 rows x 128 f ----
    const f32x4 zero4 = (f32x4){0.f, 0.f, 0.f, 0.f};
    f32x4 acc2[8];
    f16x8 aL = ldfrag(gLh + (a0 + fc) * C_N + g * 8);
    #pragma unroll
    for (int nc = 0; nc < 8; nc++) {
        int f = nc * 16 + fc;
        f16x8 bM = ldfrag(gMh + ((size_t)(b * F_N + f)) * C_N + g * 8);
        acc2[nc] = __builtin_amdgcn_mfma_f32_16x16x32_f16(aL, bM, zero4, 0, 0, 0);
    }
    #pragma unroll
    for (int nc = 0; nc < 8; nc++) {
        int f = nc * 16 + fc;
        float bo = sBout[f];
        #pragma unroll
        for (int rg = 0; rg < 4; rg++) {
            int a = a0 + g * 4 + rg;
            acc2[nc][rg] += ld(edge_vec, (a * A_N + b) * F_N + f, isbf) + bo;
        }
    }
    // wave-local LayerNorm (full 128 f in this wave)
    float mu[4], rs[4];
    #pragma unroll
    for (int rg = 0; rg < 4; rg++) {
        float p = 0.f, q = 0.f;
        #pragma unroll
        for (int nc = 0; nc < 8; nc++) { float e = acc2[nc][rg]; p += e; q += e * e; }
        p += __shfl_xor(p, 1); q += __shfl_xor(q, 1);
        p += __shfl_xor(p, 2); q += __shfl_xor(q, 2);
        p += __shfl_xor(p, 4); q += __shfl_xor(q, 4);
        p += __shfl_xor(p, 8); q += __shfl_xor(q, 8);
        float m = p * (1.0f / F_N);
        mu[rg] = m;
        rs[rg] = rsqrtf(q * (1.0f / F_N) - m * m + LN_EPS);
    }
    // X = LN(E) -> sX rows wid*16.. (wave-local region, swizzled 256B rows)
    #pragma unroll
    for (int nc = 0; nc < 8; nc++) {
        int f = nc * 16 + fc;
        float sc = sScale[f], bi = sBias[f];
        #pragma unroll
        for (int rg = 0; rg < 4; rg++) {
            int r = wid * 16 + g * 4 + rg;
            float x = (acc2[nc][rg] - mu[rg]) * rs[rg] * sc + bi;
            *(f16*)(smem + r * 256 + ((f * 2) ^ ((r & 7) << 4))) = (f16)x;
        }
    }
    // a1 fragments (wave-local read of own rows; same-wave LDS ordering)
    f16x8 a1[4];
    #pragma unroll
    for (int ks = 0; ks < 4; ks++) {
        int r = wid * 16 + fc;
        a1[ks] = ldfrag(smem + r * 256 + ((ks * 64 + g * 16) ^ ((r & 7) << 4)));
    }
    __syncthreads();            // all waves done with sX -> region becomes W1 dbuf

    // ---- prologue: DMA chunk 0 into buffer 0, drain ----
    #pragma unroll
    for (int i = 0; i < 2; i++) {
        int s = i * 4 + wid;
        gload16(gW1P + s * 64 + lane, smem + SM_W1 + s * 1024);
    }
    #pragma unroll
    for (int i = 0; i < 3; i++) {
        int s = i * 4 + wid;
        gload16(gW2P + s * 64 + lane, smem + SM_W2 + s * 1024);
    }
    __syncthreads();            // implicit vmcnt(0): buffer 0 staged

    // ---- chunk loop: 16 x 32 hidden units, ONE barrier each ----
    for (int ch = 0; ch < 16; ch++) {
        const int cur = ch & 1;
        const int h0 = ch * 32;

        // issue async DMA for chunk ch+1 (drained at end-of-chunk barrier)
        if (ch < 15) {
            const int nxt = cur ^ 1;
            #pragma unroll
            for (int i = 0; i < 2; i++) {
                int s = i * 4 + wid;
                gload16(gW1P + (ch + 1) * 512 + s * 64 + lane,
                        smem + SM_W1 + nxt * 8192 + s * 1024);
            }
            #pragma unroll
            for (int i = 0; i < 3; i++) {
                int s = i * 4 + wid;
                gload16(gW2P + (size_t)(ch + 1) * 768 + s * 64 + lane,
                        smem + SM_W2 + nxt * 12288 + s * 1024);
            }
        }

        // GEMM1: H[16r x 32h] = X(this wave) @ W1ch
        f32x4 acc1[2];
        acc1[0] = zero4; acc1[1] = zero4;
        __builtin_amdgcn_s_setprio(1);
        #pragma unroll
        for (int ks = 0; ks < 4; ks++) {
            #pragma unroll
            for (int nt = 0; nt < 2; nt++) {
                int n = nt * 16 + fc;
                f16x8 bfr = ldfrag(smem + SM_W1 + cur * 8192 + n * 256 +
                                   ((ks * 64 + g * 16) ^ ((n & 7) << 4)));
                acc1[nt] = __builtin_amdgcn_mfma_f32_16x16x32_f16(a1[ks], bfr, acc1[nt], 0, 0, 0);
            }
        }
        __builtin_amdgcn_s_setprio(0);
        // bias + relu -> H (wave-local rows, 80B stride)
        #pragma unroll
        for (int nt = 0; nt < 2; nt++) {
            int h = nt * 16 + fc;
            float b1v = sB1[h0 + h];
            #pragma unroll
            for (int rg = 0; rg < 4; rg++) {
                int r2 = wid * 16 + g * 4 + rg;
                *(f16*)(smem + SM_H + r2 * 80 + h * 2) = (f16)fmaxf(acc1[nt][rg] + b1v, 0.f);
            }
        }
        // no barrier: H produced & consumed by this wave (same-wave LDS order + lgkmcnt)
        __builtin_amdgcn_s_setprio(1);
        f16x8 afr2 = ldfrag(smem + SM_H + (wid * 16 + fc) * 80 + g * 16);
        #pragma unroll
        for (int nc = 0; nc < 8; nc++) {
            int f = nc * 16 + fc;
            f16x8 bfr2 = ldfrag(smem + SM_W2 + cur * 12288 + f * 80 + g * 16);
            acc2[nc] = __builtin_amdgcn_mfma_f32_16x16x32_f16(afr2, bfr2, acc2[nc], 0, 0, 0);
        }
        __builtin_amdgcn_s_setprio(0);
        __syncthreads();        // buffer switch: drains DMA (vmcnt0) + all LDS reads done
    }

    // ---- epilogue: out = E (in acc2) + b2 + MLP, written ONCE ----
    #pragma unroll
    for (int nc = 0; nc < 8; nc++) {
        int f = nc * 16 + fc;
        float b2v = sB2[f];
        #pragma unroll
        for (int rg = 0; rg < 4; rg++) {
            int a = a0 + g * 4 + rg;
            out[((size_t)a * A_N + b) * F_N + f] = acc2[nc][rg] + b2v;
        }
    }
}

extern "C" void kernel_launch(void* const* d_in, const int* in_sizes, int n_in,
                              void* d_out, int out_size, void* d_ws, size_t ws_size,
                              hipStream_t stream) {
    const void* node_vec  = d_in[0];
    const void* edge_vec  = d_in[1];
    const void* node_mask = d_in[2];
    // d_in[3] edge_mask: unused by reference
    const void* op_scale  = d_in[4];
    const void* op_bias   = d_in[5];
    const void* w_left    = d_in[6];
    const void* b_left    = d_in[7];
    const void* w_right   = d_in[8];
    const void* b_right   = d_in[9];
    const void* w_out     = d_in[10];
    const void* b_out     = d_in[11];
    const void* tr_scale  = d_in[12];
    const void* tr_bias   = d_in[13];
    const void* w_t1      = d_in[14];
    const void* b_t1      = d_in[15];
    const void* w_t2      = d_in[16];
    const void* b_t2      = d_in[17];
    float* out = (float*)d_out;
    (void)d_ws; (void)ws_size; (void)in_sizes; (void)n_in; (void)out_size;

    hipLaunchKernelGGL(k_pre, dim3(544), dim3(128), 0, stream,
                       node_vec, node_mask, op_scale, op_bias,
                       w_left, b_left, w_right, b_right, w_out, w_t1, w_t2);
    hipLaunchKernelGGL(k_mgemm, dim3(192), dim3(256), 0, stream);
    hipLaunchKernelGGL(k_fused, dim3(2304), dim3(256), 0, stream,
                       edge_vec, b_out, tr_scale, tr_bias, b_t1, b_t2, node_mask, out);
}

// Round 10
// 246.408 us; speedup vs baseline: 1.0284x; 1.0284x over previous
//
#include <hip/hip_runtime.h>
#include <stdint.h>
#include <stddef.h>

#define A_N 384
#define F_N 128
#define C_N 32
#define H_N 512
#define LN_EPS 1e-5f

typedef unsigned short u16;
typedef _Float16 f16;
typedef f16 f16x8 __attribute__((ext_vector_type(8)));
typedef float f32x4 __attribute__((ext_vector_type(4)));

// ---- scratch in static device memory (d_ws unused) ----
__device__ f16   gLh[A_N * C_N];            // left proj, f16 [a][c]
__device__ f16   gRh[A_N * C_N];            // right proj, f16 [b][d]
__device__ f16   gWoT[F_N * C_N * C_N];     // [fc_lin=f*32+c][d] = w_out[(c*32+d)*128+f], f16
__device__ f16   gMh[A_N * F_N * C_N];      // [b][f][c] f16 (c-contiguous = MFMA B-frag ready)
__device__ int4  gW1P[16 * 512];            // per-chunk pre-swizzled W1 LDS images (8KB each)
__device__ f16   gW2C[16 * F_N * 32];       // [ch][f][hh] = w_t2[ch*32+hh][f] (reg-frag ready)

__device__ __forceinline__ float b2f(u16 u) {
    union { float f; uint32_t i; } v; v.i = ((uint32_t)u) << 16; return v.f;
}
__device__ __forceinline__ float ld(const void* p, int idx, bool isbf) {
    if (isbf) return b2f(((const u16*)p)[idx]);
    return ((const float*)p)[idx];
}
__device__ __forceinline__ bool probe_bf16(const void* node_mask) {
    return ((const u16*)node_mask)[0] == 0x3F80u;   // 1.0 bf16; fp32 LE low half is 0x0000
}
__device__ __forceinline__ f16x8 ldfrag(const void* p) {
    union { int4 i; f16x8 h; } u; u.i = *(const int4*)p; return u.h;
}
__device__ __forceinline__ f16x8 asfrag(int4 v) {
    union { int4 i; f16x8 h; } u; u.i = v; return u.h;
}
// async global->LDS DMA, 16B per lane; lds dst must be wave-uniform base (HW adds lane*16)
__device__ __forceinline__ void gload16(const void* gsrc, void* ldst) {
    __builtin_amdgcn_global_load_lds(
        (const __attribute__((address_space(1))) void*)gsrc,
        (__attribute__((address_space(3))) void*)ldst, 16, 0, 0);
}

// ---------------- K1: k_pre — all independent prep, 128 thr/block ----------------
// blocks [0,384):   node LN + left/right projections -> gLh/gRh (f16)
// blocks [384,448): gW1P fill (pre-swizzled W1 chunk images)
// blocks [448,512): gW2C fill ([ch][f][hh], contiguous 16B per thread)
// blocks [512,544): gWoT fill (w_out transpose, 64B-contiguous writes)
__global__ __launch_bounds__(128) void k_pre(
    const void* __restrict__ node_vec, const void* __restrict__ node_mask,
    const void* __restrict__ op_scale, const void* __restrict__ op_bias,
    const void* __restrict__ w_left, const void* __restrict__ b_left,
    const void* __restrict__ w_right, const void* __restrict__ b_right,
    const void* __restrict__ w_out, const void* __restrict__ w_t1,
    const void* __restrict__ w_t2) {
    bool isbf = probe_bf16(node_mask);
    const int t = threadIdx.x;
    if (blockIdx.x < 384) {
        __shared__ float sAct[F_N];
        __shared__ float sRed[4];
        int a = blockIdx.x;
        int f = t;                      // 128 threads = 2 waves
        float x = ld(node_vec, a * F_N + f, isbf);
        float s1 = x, s2 = x * x;
        for (int o = 1; o < 64; o <<= 1) { s1 += __shfl_xor(s1, o); s2 += __shfl_xor(s2, o); }
        int wv = t >> 6;
        if ((t & 63) == 0) { sRed[wv * 2] = s1; sRed[wv * 2 + 1] = s2; }
        __syncthreads();
        float sum = sRed[0] + sRed[2], sq = sRed[1] + sRed[3];
        float mu = sum * (1.0f / F_N);
        float var = sq * (1.0f / F_N) - mu * mu;
        float rs = rsqrtf(var + LN_EPS);
        sAct[f] = (x - mu) * rs * ld(op_scale, f, isbf) + ld(op_bias, f, isbf);
        __syncthreads();
        if (t < 64) {
            int c = t & 31;
            bool isL = t < 32;
            const void* W = isL ? w_left : w_right;
            const void* B = isL ? b_left : b_right;
            float acc = ld(B, c, isbf);
            for (int ff = 0; ff < F_N; ff++) acc += sAct[ff] * ld(W, ff * C_N + c, isbf);
            acc *= ld(node_mask, a, isbf);
            if (isL) gLh[a * C_N + c] = (f16)acc;
            else     gRh[a * C_N + c] = (f16)acc;
        }
    } else if (blockIdx.x < 448) {
        int s = (blockIdx.x - 384) * 128 + t;       // 0..8191
        int ch = s >> 9, r = s & 511, n = r >> 4, sgq = r & 15;
        int h = ch * 32 + n;
        union { int4 i; f16 hh[8]; } u;
        #pragma unroll
        for (int e = 0; e < 8; e++) u.hh[e] = (f16)ld(w_t1, (sgq * 8 + e) * H_N + h, isbf);
        gW1P[ch * 512 + n * 16 + (sgq ^ (n & 7))] = u.i;
    } else if (blockIdx.x < 512) {
        int s = (blockIdx.x - 448) * 128 + t;       // 0..8191
        int ch = s >> 9, r = s & 511, f = r >> 2, hb = r & 3;
        union { int4 i; f16 hh[8]; } u;
        #pragma unroll
        for (int e = 0; e < 8; e++) u.hh[e] = (f16)ld(w_t2, (ch * 32 + hb * 8 + e) * F_N + f, isbf);
        *(int4*)(gW2C + (size_t)ch * 4096 + f * 32 + hb * 8) = u.i;
    } else {
        int row = (blockIdx.x - 512) * 128 + t;     // 0..4095
        int c = row & 31, f = row >> 5;
        union { int4 i4[4]; f16 h[32]; } u;
        #pragma unroll
        for (int d = 0; d < 32; d++) u.h[d] = (f16)ld(w_out, (c * 32 + d) * F_N + f, isbf);
        int4* dst = (int4*)(gWoT + (size_t)row * 32);
        dst[0] = u.i4[0]; dst[1] = u.i4[1]; dst[2] = u.i4[2]; dst[3] = u.i4[3];
    }
}

// ---------------- K2: k_mgemm — M[b][fc] = sum_d gRh[b,d] * gWoT[fc,d] via MFMA (unchanged) ----
__global__ __launch_bounds__(256) void k_mgemm() {
    const int t = threadIdx.x;
    const int lane = t & 63, wid = t >> 6;
    const int g = lane >> 4, fc = lane & 15;
    const int bw = wid >> 1, cw = wid & 1;
    const int bg = blockIdx.x >> 4, fg = blockIdx.x & 15;   // 12 x 16 blocks
    const int b0w = bg * 32 + bw * 16;
    const int fc0 = fg * 256 + cw * 128;
    const f32x4 zero4 = (f32x4){0.f, 0.f, 0.f, 0.f};

    f16x8 afr = ldfrag(gRh + (b0w + fc) * C_N + g * 8);
    f32x4 acc[8];
    #pragma unroll
    for (int nc = 0; nc < 8; nc++) {
        f16x8 bfr = ldfrag(gWoT + (size_t)(fc0 + nc * 16 + fc) * 32 + g * 8);
        acc[nc] = __builtin_amdgcn_mfma_f32_16x16x32_f16(afr, bfr, zero4, 0, 0, 0);
    }
    #pragma unroll
    for (int nc = 0; nc < 8; nc++) {
        int col = fc0 + nc * 16 + fc;
        #pragma unroll
        for (int rg = 0; rg < 4; rg++) {
            int b = b0w + g * 4 + rg;
            gMh[(size_t)b * 4096 + col] = (f16)acc[nc][rg];
        }
    }
}

// ---------------- K3: fused — round-8 body + W2-in-regs + H dbuf + 1 barrier/chunk ----------------
// 256 threads = 4 waves, wave grid 2x2 (wr: 2-b group, wc: 64-f half). Tile 64 rows = 4b x 16a.
// LDS 31KB -> 4 blocks/CU with launch_bounds(256,4):
//   @0     : sX f16[64][256B] (phase 1) -> W1 dbuf 2x8KB (chunk loop)
//   @16384 : H dbuf 2 x (64 x 80B) = 10240
//   @26624 : sRed 1KB | @27648 consts: B1 2KB, SCL/BIA/B2/BOUT 512B each
#define SM_W1   0
#define SM_H    16384
#define SM_RED  26624
#define SM_B1   27648
#define SM_SCL  29696
#define SM_BIA  30208
#define SM_B2   30720
#define SM_BOUT 31232
#define SM_TOT  31744

__global__ __launch_bounds__(256, 4) void k_fused(
    const void* __restrict__ edge_vec, const void* __restrict__ b_out,
    const void* __restrict__ tr_scale, const void* __restrict__ tr_bias,
    const void* __restrict__ b_t1, const void* __restrict__ b_t2,
    const void* __restrict__ node_mask, float* __restrict__ out)
{
    bool isbf = probe_bf16(node_mask);
    __shared__ __align__(16) unsigned char smem[SM_TOT];
    float* sRed   = (float*)(smem + SM_RED);
    float* sB1    = (float*)(smem + SM_B1);
    float* sScale = (float*)(smem + SM_SCL);
    float* sBias  = (float*)(smem + SM_BIA);
    float* sB2    = (float*)(smem + SM_B2);
    float* sBout  = (float*)(smem + SM_BOUT);

    const int t = threadIdx.x;               // 256 threads = 4 waves
    const int lane = t & 63, wid = t >> 6;
    const int g = lane >> 4, fc = lane & 15;
    const int wr = wid >> 1, wc = wid & 1;

    // Bijective XCD remap: 2304 blocks = 8 xcd x (12 bx x 24 by)
    const int L = blockIdx.x;
    const int xcd = L & 7, pos = L >> 3;
    const int bx = xcd * 12 + (pos % 12);
    const int by = pos / 12;
    const int a0 = by * 16, b0 = bx * 4;

    // ---- phase 0: consts ----
    sB1[t]       = ld(b_t1, t, isbf);
    sB1[t + 256] = ld(b_t1, t + 256, isbf);
    if (t < 128) {
        sScale[t] = ld(tr_scale, t, isbf);
        sBias[t]  = ld(tr_bias, t, isbf);
        sB2[t]    = ld(b_t2, t, isbf);
        sBout[t]  = ld(b_out, t, isbf);
    }
    __syncthreads();

    // ---- phase 1: E via MFMA, directly in accumulator layout (round-8 proven) ----
    f32x4 acc2[2][4];
    const f32x4 zero4 = (f32x4){0.f, 0.f, 0.f, 0.f};
    f16x8 aL = ldfrag(gLh + (a0 + fc) * C_N + g * 8);
    #pragma unroll
    for (int bb = 0; bb < 2; bb++) {
        int b = b0 + wr * 2 + bb;
        #pragma unroll
        for (int nc = 0; nc < 4; nc++) {
            int f = wc * 64 + nc * 16 + fc;
            f16x8 bM = ldfrag(gMh + ((size_t)(b * F_N + f)) * C_N + g * 8);
            acc2[bb][nc] = __builtin_amdgcn_mfma_f32_16x16x32_f16(aL, bM, zero4, 0, 0, 0);
        }
    }
    #pragma unroll
    for (int bb = 0; bb < 2; bb++) {
        int b = b0 + wr * 2 + bb;
        #pragma unroll
        for (int nc = 0; nc < 4; nc++) {
            int f = wc * 64 + nc * 16 + fc;
            float bo = sBout[f];
            #pragma unroll
            for (int rg = 0; rg < 4; rg++) {
                int a = a0 + g * 4 + rg;
                acc2[bb][nc][rg] += ld(edge_vec, (a * A_N + b) * F_N + f, isbf) + bo;
            }
        }
    }
    // in-register LayerNorm with cross-wc exchange
    float pA[2][4], qA[2][4];
    #pragma unroll
    for (int bb = 0; bb < 2; bb++)
        #pragma unroll
        for (int rg = 0; rg < 4; rg++) {
            float e0 = acc2[bb][0][rg], e1 = acc2[bb][1][rg];
            float e2 = acc2[bb][2][rg], e3 = acc2[bb][3][rg];
            float p = e0 + e1 + e2 + e3;
            float q = e0 * e0 + e1 * e1 + e2 * e2 + e3 * e3;
            p += __shfl_xor(p, 1); q += __shfl_xor(q, 1);
            p += __shfl_xor(p, 2); q += __shfl_xor(q, 2);
            p += __shfl_xor(p, 4); q += __shfl_xor(q, 4);
            p += __shfl_xor(p, 8); q += __shfl_xor(q, 8);
            pA[bb][rg] = p; qA[bb][rg] = q;
            if (fc == 0) {
                int r = wr * 32 + bb * 16 + g * 4 + rg;
                sRed[r * 4 + wc * 2]     = p;
                sRed[r * 4 + wc * 2 + 1] = q;
            }
        }
    __syncthreads();
    float muA[2][4], rsA[2][4];
    #pragma unroll
    for (int bb = 0; bb < 2; bb++)
        #pragma unroll
        for (int rg = 0; rg < 4; rg++) {
            int r = wr * 32 + bb * 16 + g * 4 + rg;
            float s1 = pA[bb][rg] + sRed[r * 4 + (wc ^ 1) * 2];
            float s2 = qA[bb][rg] + sRed[r * 4 + (wc ^ 1) * 2 + 1];
            float mu = s1 * (1.0f / F_N);
            float var = s2 * (1.0f / F_N) - mu * mu;
            muA[bb][rg] = mu;
            rsA[bb][rg] = rsqrtf(var + LN_EPS);
        }
    // X = LN(E) -> sX (f16, swizzled 256B rows)
    #pragma unroll
    for (int bb = 0; bb < 2; bb++)
        #pragma unroll
        for (int nc = 0; nc < 4; nc++) {
            int f = wc * 64 + nc * 16 + fc;
            float sc = sScale[f], bi = sBias[f];
            #pragma unroll
            for (int rg = 0; rg < 4; rg++) {
                int r = wr * 32 + bb * 16 + g * 4 + rg;
                float x = (acc2[bb][nc][rg] - muA[bb][rg]) * rsA[bb][rg] * sc + bi;
                *(f16*)(smem + r * 256 + ((f * 2) ^ ((r & 7) << 4))) = (f16)x;
            }
        }
    __syncthreads();

    // ---- phase 2: X fragments -> registers ----
    f16x8 a1[2][4];
    #pragma unroll
    for (int mr = 0; mr < 2; mr++)
        #pragma unroll
        for (int ks = 0; ks < 4; ks++) {
            int r = wr * 32 + mr * 16 + fc;
            a1[mr][ks] = ldfrag(smem + r * 256 + ((ks * 64 + g * 16) ^ ((r & 7) << 4)));
        }
    __syncthreads();            // sX reads done -> region becomes W1 dbuf

    // ---- prologue: DMA W1 chunk 0 into buffer 0, drain ----
    #pragma unroll
    for (int i = 0; i < 2; i++) {
        int s = i * 4 + wid;
        gload16(gW1P + s * 64 + lane, smem + SM_W1 + s * 1024);
    }
    __syncthreads();            // implicit vmcnt(0): buffer 0 staged

    // ---- chunk loop: 16 x 32 hidden units, ONE barrier each ----
    const f16* w2base = gW2C + (wc * 64 + fc) * 32 + g * 8;
    for (int ch = 0; ch < 16; ch++) {
        const int cur = ch & 1;
        const int h0 = ch * 32;

        // W2 frags for THIS chunk: global->regs (L2-hot; covered by GEMM1+relu)
        const f16* wb = w2base + (size_t)ch * 4096;
        int4 w2ra = *(const int4*)(wb);
        int4 w2rb = *(const int4*)(wb + 512);
        int4 w2rc = *(const int4*)(wb + 1024);
        int4 w2rd = *(const int4*)(wb + 1536);

        // W1 DMA for chunk ch+1 into alternate buffer (drains at this chunk's barrier)
        if (ch < 15) {
            #pragma unroll
            for (int i = 0; i < 2; i++) {
                int s = i * 4 + wid;
                gload16(gW1P + (ch + 1) * 512 + s * 64 + lane,
                        smem + SM_W1 + (cur ^ 1) * 8192 + s * 1024);
            }
        }

        // GEMM1: H[64r x 32h] = X @ W1ch ; wave tile 32r x 16h (a1 + W1-LDS)
        f32x4 acc1[2];
        acc1[0] = zero4; acc1[1] = zero4;
        __builtin_amdgcn_s_setprio(1);
        #pragma unroll
        for (int ks = 0; ks < 4; ks++) {
            int n = wc * 16 + fc;
            f16x8 bfr = ldfrag(smem + SM_W1 + cur * 8192 + n * 256 +
                               ((ks * 64 + g * 16) ^ ((n & 7) << 4)));
            #pragma unroll
            for (int mr = 0; mr < 2; mr++)
                acc1[mr] = __builtin_amdgcn_mfma_f32_16x16x32_f16(a1[mr][ks], bfr, acc1[mr], 0, 0, 0);
        }
        __builtin_amdgcn_s_setprio(0);
        // bias + relu -> H[cur] (80B rows)
        {
            int jl = wc * 16 + fc;
            float b1v = sB1[h0 + jl];
            #pragma unroll
            for (int mr = 0; mr < 2; mr++)
                #pragma unroll
                for (int rg = 0; rg < 4; rg++) {
                    int r2 = wr * 32 + mr * 16 + g * 4 + rg;
                    *(f16*)(smem + SM_H + cur * 5120 + r2 * 80 + jl * 2) =
                        (f16)fmaxf(acc1[mr][rg] + b1v, 0.f);
                }
        }
        __syncthreads();        // H[cur] ready; DMA drained; W2 regs landed

        // GEMM2: acc2 += H[cur] @ W2regs ; wave tile 32r x 64f
        __builtin_amdgcn_s_setprio(1);
        {
            f16x8 afr0 = ldfrag(smem + SM_H + cur * 5120 + (wr * 32 + fc) * 80 + g * 16);
            f16x8 afr1 = ldfrag(smem + SM_H + cur * 5120 + (wr * 32 + 16 + fc) * 80 + g * 16);
            f16x8 b0f = asfrag(w2ra), b1f = asfrag(w2rb), b2f2 = asfrag(w2rc), b3f = asfrag(w2rd);
            acc2[0][0] = __builtin_amdgcn_mfma_f32_16x16x32_f16(afr0, b0f, acc2[0][0], 0, 0, 0);
            acc2[1][0] = __builtin_amdgcn_mfma_f32_16x16x32_f16(afr1, b0f, acc2[1][0], 0, 0, 0);
            acc2[0][1] = __builtin_amdgcn_mfma_f32_16x16x32_f16(afr0, b1f, acc2[0][1], 0, 0, 0);
            acc2[1][1] = __builtin_amdgcn_mfma_f32_16x16x32_f16(afr1, b1f, acc2[1][1], 0, 0, 0);
            acc2[0][2] = __builtin_amdgcn_mfma_f32_16x16x32_f16(afr0, b2f2, acc2[0][2], 0, 0, 0);
            acc2[1][2] = __builtin_amdgcn_mfma_f32_16x16x32_f16(afr1, b2f2, acc2[1][2], 0, 0, 0);
            acc2[0][3] = __builtin_amdgcn_mfma_f32_16x16x32_f16(afr0, b3f, acc2[0][3], 0, 0, 0);
            acc2[1][3] = __builtin_amdgcn_mfma_f32_16x16x32_f16(afr1, b3f, acc2[1][3], 0, 0, 0);
        }
        __builtin_amdgcn_s_setprio(0);
        // no end-of-chunk barrier: H dbuf + DMA-after-barrier make it safe
    }

    // ---- epilogue: out = E (in acc2) + b2 + MLP, written ONCE ----
    #pragma unroll
    for (int bb = 0; bb < 2; bb++) {
        int b = b0 + wr * 2 + bb;
        #pragma unroll
        for (int nc = 0; nc < 4; nc++) {
            int f = wc * 64 + nc * 16 + fc;
            float b2v = sB2[f];
            #pragma unroll
            for (int rg = 0; rg < 4; rg++) {
                int a = a0 + g * 4 + rg;
                out[((size_t)a * A_N + b) * F_N + f] = acc2[bb][nc][rg] + b2v;
            }
        }
    }
}

extern "C" void kernel_launch(void* const* d_in, const int* in_sizes, int n_in,
                              void* d_out, int out_size, void* d_ws, size_t ws_size,
                              hipStream_t stream) {
    const void* node_vec  = d_in[0];
    const void* edge_vec  = d_in[1];
    const void* node_mask = d_in[2];
    // d_in[3] edge_mask: unused by reference
    const void* op_scale  = d_in[4];
    const void* op_bias   = d_in[5];
    const void* w_left    = d_in[6];
    const void* b_left    = d_in[7];
    const void* w_right   = d_in[8];
    const void* b_right   = d_in[9];
    const void* w_out     = d_in[10];
    const void* b_out     = d_in[11];
    const void* tr_scale  = d_in[12];
    const void* tr_bias   = d_in[13];
    const void* w_t1      = d_in[14];
    const void* b_t1      = d_in[15];
    const void* w_t2      = d_in[16];
    const void* b_t2      = d_in[17];
    float* out = (float*)d_out;
    (void)d_ws; (void)ws_size; (void)in_sizes; (void)n_in; (void)out_size;

    hipLaunchKernelGGL(k_pre, dim3(544), dim3(128), 0, stream,
                       node_vec, node_mask, op_scale, op_bias,
                       w_left, b_left, w_right, b_right, w_out, w_t1, w_t2);
    hipLaunchKernelGGL(k_mgemm, dim3(192), dim3(256), 0, stream);
    hipLaunchKernelGGL(k_fused, dim3(2304), dim3(256), 0, stream,
                       edge_vec, b_out, tr_scale, tr_bias, b_t1, b_t2, node_mask, out);
}